// Round 7
// baseline (1060.402 us; speedup 1.0000x reference)
//
#include <hip/hip_runtime.h>
#include <hip/hip_bf16.h>
#include <math.h>

#define IGNORE_INDEX (-100)

typedef __attribute__((ext_vector_type(4))) float f32x4;
typedef __attribute__((ext_vector_type(16))) float f32x16;
typedef __attribute__((ext_vector_type(4))) int i32x4;
typedef __attribute__((ext_vector_type(8))) int i32x8;

// Problem sizes (fixed by the reference)
static const int NTOK = 2 * 4096;   // 8192 tokens (GEMM M)
static const int DIM  = 2048;       // embed dim (GEMM K)
static const int VOC  = 32000;      // vocab (GEMM N)
static const int BM = 256, BN = 256;
static const int KS = 64;           // K per slot
static const int NPH = DIM / KS;    // 32 slots
static const int NVT = VOC / BN;    // 125 vocab tiles
static const int MT  = NTOK / BM;   // 32 m tiles
static const float WSCALE = 16.0f;  // W pre-scale (exact power of 2)
#define SCL1 0x7F7F7F7F             // e8m0 scale byte 0x7F = 2^0 = 1.0 (all bytes)

// ---------------- helpers ----------------

__device__ inline void gload_lds16(const void* g, void* l) {
  __builtin_amdgcn_global_load_lds(
      (const __attribute__((address_space(1))) void*)g,
      (__attribute__((address_space(3))) void*)l,
      16, 0, 0);
}

// ---------------- kernel 1: fp32 -> fp8 e4m3 cast (with scale) ----------------

__global__ void cast_f32_fp8(const float* __restrict__ in,
                             unsigned char* __restrict__ out, long n8, float scale) {
  long i0 = (long)blockIdx.x * blockDim.x + threadIdx.x;
  long stride = (long)gridDim.x * blockDim.x;
  for (long i = i0; i < n8; i += stride) {
    const float4* p = (const float4*)(in + i * 8);
    float4 a = p[0], b = p[1];
    int lo = __builtin_amdgcn_cvt_pk_fp8_f32(a.x * scale, a.y * scale, 0, false);
    lo = __builtin_amdgcn_cvt_pk_fp8_f32(a.z * scale, a.w * scale, lo, true);
    int hi = __builtin_amdgcn_cvt_pk_fp8_f32(b.x * scale, b.y * scale, 0, false);
    hi = __builtin_amdgcn_cvt_pk_fp8_f32(b.z * scale, b.w * scale, hi, true);
    int2 o; o.x = lo; o.y = hi;
    *(int2*)(out + i * 8) = o;
  }
}

// ---------------- kernel 2: 256x256 MX-fp8 MFMA GEMM (32x32x64, scale=1.0) ----------------
// LDS: A ring = 4 slots x 16KB at smem[0]; B ring at smem[64K]. 128KB dynamic.
// Slot layout (fragment-major, lane-linear): frag f (32 rows x 64 k-bytes, 2KB) at
// slot*16384 + f*2048; half h (1KB) holds each lane's h-th 16B chunk at h*1024 + lane*16.
// Lane l operand = global row (l&31), k-bytes (l>>5)*32 .. +32 (matches f8f6f4 A/B map).
// Staging: per-lane global source row=(l&31), col=kt+(l>>5)*32+h*16 -> linear LDS dest.
// Both ds_write (via gload_lds) and ds_read_b128 are lane-linear => 0 conflicts (R6-verified).

#define VM8  asm volatile("s_waitcnt vmcnt(8)" ::: "memory")
#define VM4  asm volatile("s_waitcnt vmcnt(4)" ::: "memory")
#define VM0  asm volatile("s_waitcnt vmcnt(0)" ::: "memory")
#define BARRIER asm volatile("s_barrier" ::: "memory")
#define LGKM0 asm volatile("s_waitcnt lgkmcnt(0)" ::: "memory")

// MX-scaled MFMA, fmt fp8(e4m3)=0 for A and B, scale = 1.0 (0x7F), opsel byte 0
#define MS(ACC, AV, BV) \
  ACC = __builtin_amdgcn_mfma_scale_f32_32x32x64_f8f6f4( \
      AV, BV, ACC, 0, 0, 0, SCL1, 0, SCL1)

#define PACK8(LO, HI) {LO[0], LO[1], LO[2], LO[3], HI[0], HI[1], HI[2], HI[3]}

__launch_bounds__(512, 2)
__global__ void lce_gemm(const unsigned char* __restrict__ xq,
                         const unsigned char* __restrict__ wq,
                         float* __restrict__ pmax, float* __restrict__ psum) {
  extern __shared__ char smem[];
  char* smA = smem;
  char* smB = smem + 65536;

  // XCD-aware swizzle (nwg = 4000, divisible by 8), mt-minor
  const int nwg = NVT * MT;            // 4000
  const int cpx = nwg >> 3;            // 500
  const int bid = blockIdx.x;
  const int swz = (bid & 7) * cpx + (bid >> 3);
  const int vt = swz / MT;
  const int mt = swz % MT;
  const int m0 = mt * BM;
  const int v0 = vt * BN;

  const int tid = threadIdx.x;
  const int lane = tid & 63;
  const int w = tid >> 6;              // 0..7
  const int wr = w >> 2, wc = w & 3;   // 2 x 4 wave grid; wave tile 128x64
  const int lc = lane & 31;            // col/row-in-frag
  const int lh = lane >> 5;            // k-half selector

  f32x16 acc[4][2];
#pragma unroll
  for (int i = 0; i < 4; ++i)
#pragma unroll
    for (int j = 0; j < 2; ++j)
#pragma unroll
      for (int r = 0; r < 16; ++r) acc[i][j][r] = 0.f;

  // ---- staging: wave w stages A frag w (2 gloads) + B frag w (2 gloads) per slot ----
  const unsigned char* aS0 = xq + (long)(m0 + w * 32 + lc) * DIM + lh * 32;
  const unsigned char* aS1 = aS0 + 16;
  const unsigned char* bS0 = wq + (long)(v0 + w * 32 + lc) * DIM + lh * 32;
  const unsigned char* bS1 = bS0 + 16;
  char* stA = smA + w * 2048;          // frag w base; halves at +0 / +1024
  char* stB = smB + w * 2048;

  // ---- ds_read bases (lane-linear) ----
  const char* aRd = smA + wr * 4 * 2048 + lane * 16;   // + slot*16384 + i*2048 (+1024 hi)
  const char* bRd = smB + wc * 2 * 2048 + lane * 16;   // + slot*16384 + j*2048 (+1024 hi)

  // ---- prologue: stage slots 0,1,2 (4 loads/slot/wave = 12) ----
#pragma unroll
  for (int s = 0; s < 3; ++s) {
    gload_lds16(aS0, stA + s * 16384);        aS0 += KS;
    gload_lds16(aS1, stA + s * 16384 + 1024); aS1 += KS;
    gload_lds16(bS0, stB + s * 16384);        bS0 += KS;
    gload_lds16(bS1, stB + s * 16384 + 1024); bS1 += KS;
  }
  VM8;   // slot 0's 4 loads done
  BARRIER;

  // ---- main loop: 32 slots x 2 fine phases of 4 MFMA (K=64 each) ----
#pragma unroll 1
  for (int n = 0; n < NPH; ++n) {
    const int slot = n & 3;
    const int dst = (n + 3) & 3;
    const char* Ab = aRd + slot * 16384;
    const char* Bb = bRd + slot * 16384;
    const bool stg = (n < NPH - 3);

    // phase 0: read B0,B1 + A0,A1 (8 b128), stage A halves; MFMA rows 0-63
    i32x4 b0l = *(const i32x4*)(Bb);
    i32x4 b0h = *(const i32x4*)(Bb + 1024);
    i32x4 b1l = *(const i32x4*)(Bb + 2048);
    i32x4 b1h = *(const i32x4*)(Bb + 3072);
    i32x4 a0l = *(const i32x4*)(Ab);
    i32x4 a0h = *(const i32x4*)(Ab + 1024);
    i32x4 a1l = *(const i32x4*)(Ab + 2048);
    i32x4 a1h = *(const i32x4*)(Ab + 3072);
    if (stg) {
      gload_lds16(aS0, stA + dst * 16384);        aS0 += KS;
      gload_lds16(aS1, stA + dst * 16384 + 1024); aS1 += KS;
    }
    BARRIER; LGKM0;
    {
      i32x8 B0 = PACK8(b0l, b0h);
      i32x8 B1 = PACK8(b1l, b1h);
      i32x8 A0 = PACK8(a0l, a0h);
      i32x8 A1 = PACK8(a1l, a1h);
      __builtin_amdgcn_s_setprio(1);
      MS(acc[0][0], A0, B0); MS(acc[0][1], A0, B1);
      MS(acc[1][0], A1, B0); MS(acc[1][1], A1, B1);
      __builtin_amdgcn_s_setprio(0);
    }
    BARRIER;

    // phase 1: read A2,A3 (4 b128), stage B halves; MFMA rows 64-127
    i32x4 a2l = *(const i32x4*)(Ab + 4096);
    i32x4 a2h = *(const i32x4*)(Ab + 5120);
    i32x4 a3l = *(const i32x4*)(Ab + 6144);
    i32x4 a3h = *(const i32x4*)(Ab + 7168);
    if (stg) {
      gload_lds16(bS0, stB + dst * 16384);        bS0 += KS;
      gload_lds16(bS1, stB + dst * 16384 + 1024); bS1 += KS;
    }
    BARRIER; LGKM0;
    {
      i32x8 B0 = PACK8(b0l, b0h);
      i32x8 B1 = PACK8(b1l, b1h);
      i32x8 A2 = PACK8(a2l, a2h);
      i32x8 A3 = PACK8(a3l, a3h);
      __builtin_amdgcn_s_setprio(1);
      MS(acc[2][0], A2, B0); MS(acc[2][1], A2, B1);
      MS(acc[3][0], A3, B0); MS(acc[3][1], A3, B1);
      __builtin_amdgcn_s_setprio(0);
    }
    if (n < NPH - 3) { VM8; }
    else if (n == NPH - 3) { VM4; }
    else if (n == NPH - 2) { VM0; }
    BARRIER;
  }

  // ---- epilogue: per-row max & sum(exp) over this tile's 256 cols; logits = acc/WSCALE ----
  // 32x32 C/D layout (verified m74/m101): col = lane&31, row = (r&3) + 8*(r>>2) + 4*(lane>>5)
  const float sc = 1.0f / WSCALE;
  float* sm_m = (float*)smem;          // [4][256]
  float* sm_s = (float*)(smem + 4096); // [4][256]
  __syncthreads();                     // loop fully drained; safe to reuse LDS
#pragma unroll
  for (int i = 0; i < 4; ++i) {
#pragma unroll
    for (int r = 0; r < 16; ++r) {
      float l0 = acc[i][0][r] * sc, l1 = acc[i][1][r] * sc;
      float m = fmaxf(l0, l1);
#pragma unroll
      for (int mk = 1; mk < 32; mk <<= 1) m = fmaxf(m, __shfl_xor(m, mk));
      float s = __expf(l0 - m) + __expf(l1 - m);
#pragma unroll
      for (int mk = 1; mk < 32; mk <<= 1) s += __shfl_xor(s, mk);
      if (lc == 0) {
        int R = wr * 128 + i * 32 + (r & 3) + 8 * (r >> 2) + 4 * lh;
        sm_m[wc * 256 + R] = m;
        sm_s[wc * 256 + R] = s;
      }
    }
  }
  __syncthreads();
  if (tid < BM) {
    float ma = sm_m[tid], mb = sm_m[256 + tid], mc = sm_m[512 + tid], md = sm_m[768 + tid];
    float gm = fmaxf(fmaxf(ma, mb), fmaxf(mc, md));
    float gs = sm_s[tid] * __expf(ma - gm) + sm_s[256 + tid] * __expf(mb - gm) +
               sm_s[512 + tid] * __expf(mc - gm) + sm_s[768 + tid] * __expf(md - gm);
    long row = (long)(m0 + tid);
    pmax[row * NVT + vt] = gm;
    psum[row * NVT + vt] = gs;
  }
}

// ---------------- kernel 3: per-token LSE combine + exact fp32 target dot ----------------

__global__ void token_reduce(const float* __restrict__ x, const float* __restrict__ wgt,
                             const int* __restrict__ tgt,
                             const float* __restrict__ pmax, const float* __restrict__ psum,
                             float* __restrict__ nll, float* __restrict__ validf) {
  const int n = blockIdx.x;
  const int tid = threadIdx.x;
  const int lane = tid & 63;
  const int w = tid >> 6;
  __shared__ float smr[4];

  const int t = tgt[n];
  const bool valid = (t != IGNORE_INDEX);
  const int ts = valid ? t : 0;

  // exact fp32 target logit
  const float4* xr = (const float4*)(x + (long)n * DIM);
  const float4* wr = (const float4*)(wgt + (long)ts * DIM);
  float d = 0.f;
  for (int i = tid; i < DIM / 4; i += blockDim.x) {
    float4 a = xr[i], b = wr[i];
    d += a.x * b.x + a.y * b.y + a.z * b.z + a.w * b.w;
  }

  // LSE over 125 partials
  float m = (tid < NVT) ? pmax[(long)n * NVT + tid] : -INFINITY;
  float t1 = m;
#pragma unroll
  for (int mk = 1; mk < 64; mk <<= 1) t1 = fmaxf(t1, __shfl_xor(t1, mk));
  if (lane == 0) smr[w] = t1;
  __syncthreads();
  const float gm = fmaxf(fmaxf(smr[0], smr[1]), fmaxf(smr[2], smr[3]));
  __syncthreads();

  float se = (tid < NVT) ? psum[(long)n * NVT + tid] * __expf(m - gm) : 0.f;
#pragma unroll
  for (int mk = 1; mk < 64; mk <<= 1) se += __shfl_xor(se, mk);
  if (lane == 0) smr[w] = se;
  __syncthreads();
  const float gs = smr[0] + smr[1] + smr[2] + smr[3];
  __syncthreads();

#pragma unroll
  for (int mk = 1; mk < 64; mk <<= 1) d += __shfl_xor(d, mk);
  if (lane == 0) smr[w] = d;
  __syncthreads();
  const float gd = smr[0] + smr[1] + smr[2] + smr[3];

  if (tid == 0) {
    nll[n] = valid ? (gm + logf(gs) - gd) : 0.f;
    validf[n] = valid ? 1.f : 0.f;
  }
}

// ---------------- kernel 4: deterministic final mean ----------------

__global__ void final_reduce(const float* __restrict__ nll, const float* __restrict__ validf,
                             float* __restrict__ out, int n) {
  const int tid = threadIdx.x;
  const int lane = tid & 63;
  const int w = tid >> 6;
  __shared__ float sm1[4], sm2[4];
  float s = 0.f, c = 0.f;
  for (int i = tid; i < n; i += blockDim.x) { s += nll[i]; c += validf[i]; }
#pragma unroll
  for (int mk = 1; mk < 64; mk <<= 1) { s += __shfl_xor(s, mk); c += __shfl_xor(c, mk); }
  if (lane == 0) { sm1[w] = s; sm2[w] = c; }
  __syncthreads();
  if (tid == 0) {
    float ts = sm1[0] + sm1[1] + sm1[2] + sm1[3];
    float tc = sm2[0] + sm2[1] + sm2[2] + sm2[3];
    out[0] = ts / fmaxf(tc, 1.0f);
  }
}

// ---------------- launch ----------------

extern "C" void kernel_launch(void* const* d_in, const int* in_sizes, int n_in,
                              void* d_out, int out_size, void* d_ws, size_t ws_size,
                              hipStream_t stream) {
  const float* x = (const float*)d_in[0];     // [8192, 2048] fp32
  const float* wgt = (const float*)d_in[1];   // [32000, 2048] fp32
  const int* tgt = (const int*)d_in[2];       // [8192] int
  float* out = (float*)d_out;

  char* ws = (char*)d_ws;
  const size_t xq_off = 0;
  const size_t wq_off = (size_t)NTOK * DIM;                        // 16,777,216
  const size_t pm_off = wq_off + (size_t)VOC * DIM;                // 82,313,216
  const size_t ps_off = pm_off + (size_t)NTOK * NVT * 4;
  const size_t nl_off = ps_off + (size_t)NTOK * NVT * 4;
  const size_t vf_off = nl_off + (size_t)NTOK * 4;
  const size_t needed = vf_off + (size_t)NTOK * 4;
  if (ws_size < needed) return;  // workspace too small: fail visibly

  unsigned char* xq = (unsigned char*)(ws + xq_off);
  unsigned char* wq = (unsigned char*)(ws + wq_off);
  float* pmax = (float*)(ws + pm_off);
  float* psum = (float*)(ws + ps_off);
  float* nllv = (float*)(ws + nl_off);
  float* vldf = (float*)(ws + vf_off);

  cast_f32_fp8<<<2048, 256, 0, stream>>>(x, xq, (long)NTOK * DIM / 8, 1.0f);
  cast_f32_fp8<<<4096, 256, 0, stream>>>(wgt, wq, (long)VOC * DIM / 8, WSCALE);

  (void)hipFuncSetAttribute((const void*)lce_gemm,
                            hipFuncAttributeMaxDynamicSharedMemorySize, 131072);
  lce_gemm<<<NVT * MT, 512, 131072, stream>>>(xq, wq, pmax, psum);

  token_reduce<<<NTOK, 256, 0, stream>>>(x, wgt, tgt, pmax, psum, nllv, vldf);
  final_reduce<<<1, 256, 0, stream>>>(nllv, vldf, out, NTOK);
}